// Round 4
// baseline (130.563 us; speedup 1.0000x reference)
//
#include <hip/hip_runtime.h>
#include <hip/hip_bf16.h>

// SupCon loss, N=8192, D=128, T=0.1.
// R3: (a) gather-based class-sum kernel (removes 1M global atomics from
// normalize), (b) Gram-symmetry main: only upper-triangle tiles computed,
// each tile feeds row-sums AND col-sums (block-level LDS combine for cols),
// (c) no memset node. 4 graph nodes total.
//
// Math: loss_i = (cnt_i*lse_i - ps_i)/(cnt_i+tiny)
//   lse_i = 10 + ln(sum_{j!=i} e^{s_ij-10})   (constant shift exact; s<=10)
//   ps_i  = 10*(x_i . csum[lab_i] - x_i . x_i)
//   se accumulated INCLUDING diagonal; diag e^{10*selfdot-10} subtracted in
//   finalize. Symmetry: e(r,c) of tile (I,J), J>I contributes to se[r] and se[c].

typedef __bf16 bf16_t;
typedef __bf16 bf16x2 __attribute__((ext_vector_type(2)));
typedef __bf16 bf16x8 __attribute__((ext_vector_type(8)));
typedef float f32x16 __attribute__((ext_vector_type(16)));

#define NN 8192
#define DIM 128
#define NCLASS 1024
#define NJOBS 4224               // sum over octets o<32 of 8*(32-o)
#define SMALL_VAL 1.17549435e-38f
#define L2E10 14.4269504089f     // 10*log2(e)
#define LN2 0.69314718056f

// Swizzle: X[row][d] at (row>>5)*4096 + (d>>4)*512 + ((d>>3)&1)*256 + (row&31)*8 + (d&7)
// Lane slot: lane l holds dims (2l, 2l+1) at f=l>>3, hh=(l>>2)&1, j=(l&3)*2.

// --- normalize + swizzle store; zero se_acc and out ---
__global__ __launch_bounds__(256) void normalize_kernel(const float* __restrict__ emb,
                                                        bf16_t* __restrict__ xsw,
                                                        float* __restrict__ se_acc,
                                                        float* __restrict__ out) {
    int row  = blockIdx.x * 4 + (threadIdx.x >> 6);
    int lane = threadIdx.x & 63;
    float2 v = ((const float2*)emb)[row * 64 + lane];
    float ss = v.x * v.x + v.y * v.y;
#pragma unroll
    for (int m = 1; m < 64; m <<= 1) ss += __shfl_xor(ss, m, 64);
    float inv = 1.0f / fmaxf(sqrtf(ss), 1e-12f);
    bf16x2 o; o.x = (bf16_t)(v.x * inv); o.y = (bf16_t)(v.y * inv);
    int f = lane >> 3, hh = (lane >> 2) & 1, j = (lane & 3) << 1;
    *(bf16x2*)(xsw + ((size_t)(row >> 5) * 4096) + f * 512 + hh * 256 + (row & 31) * 8 + j) = o;
    if (threadIdx.x < 4) se_acc[blockIdx.x * 4 + threadIdx.x] = 0.f;
    if (blockIdx.x == 0 && threadIdx.x == 0) *out = 0.f;
}

// --- class sums by gather: one wave per class, ballot-scan labels ---
__global__ __launch_bounds__(256) void csum_kernel(const bf16_t* __restrict__ xsw,
                                                   const int* __restrict__ labels,
                                                   float* __restrict__ csum,
                                                   int* __restrict__ hist) {
    int wv = threadIdx.x >> 6, lane = threadIdx.x & 63;
    int cls = blockIdx.x * 4 + wv;           // 256 blocks -> classes 0..1023
    int f = lane >> 3, hh = (lane >> 2) & 1, j = (lane & 3) << 1;
    float s0 = 0.f, s1 = 0.f;
    int cnt = 0;
    for (int k = 0; k < NN; k += 64) {
        int lab = labels[k + lane];
        unsigned long long m = __ballot(lab == cls);
        cnt += __popcll(m);
        while (m) {
            int b = __builtin_ctzll(m);
            m &= m - 1;
            int row = k + b;
            bf16x2 xv = *(const bf16x2*)(xsw + ((size_t)(row >> 5) * 4096) + f * 512 + hh * 256 + (row & 31) * 8 + j);
            s0 += (float)xv.x; s1 += (float)xv.y;
        }
    }
    *(float2*)(csum + (size_t)cls * DIM + 2 * lane) = float2{s0, s1};
    if (lane == 0) hist[cls] = cnt;
}

#define MFMA8(acc, bb)                                                          \
    do {                                                                        \
        _Pragma("unroll")                                                       \
        for (int f_ = 0; f_ < 8; ++f_)                                          \
            acc = __builtin_amdgcn_mfma_f32_32x32x16_bf16(a[f_], bb[f_], acc, 0, 0, 0); \
    } while (0)

// --- main: upper-triangle jobs. Wave-job w -> (I = 32-row band, ci = 256-col chunk),
// ci >= I>>3. Tiles t=0..7 cover col-bands ci*8+t; tiles with ct<I masked,
// ct==I row-side only, ct>I row+col. 4 waves/block share ci -> LDS col combine.
// C layout (m74/m101): col = lane&31, row = (r&3) + 8*(r>>2) + 4*(lane>>5).
__global__ __launch_bounds__(256, 3) void supcon_main(const bf16_t* __restrict__ xsw,
                                                      float* __restrict__ se_acc) {
    __shared__ float cols[256];
    cols[threadIdx.x] = 0.f;
    __syncthreads();

    int wv = threadIdx.x >> 6, lane = threadIdx.x & 63;
    int w = blockIdx.x * 4 + wv;
    int o = 0, cum = 0;
    while (o < 31 && cum + 8 * (32 - o) <= w) { cum += 8 * (32 - o); ++o; }
    int jr = w - cum;
    int ci = o + (jr >> 3);       // column chunk (same for all 4 waves of block)
    int I  = 8 * o + (jr & 7);    // row band

    int c = lane & 31, h = lane >> 5;
    int laneoff = h * 256 + c * 8;

    const bf16_t* abase = xsw + (size_t)I * 4096 + laneoff;
    bf16x8 a[8];
#pragma unroll
    for (int f = 0; f < 8; ++f) a[f] = *(const bf16x8*)(abase + f * 512);

    const bf16_t* bbase = xsw + (size_t)ci * 8 * 4096 + laneoff;

    float se[16], colacc[8];
#pragma unroll
    for (int r = 0; r < 16; ++r) se[r] = 0.f;
#pragma unroll
    for (int t = 0; t < 8; ++t) colacc[t] = 0.f;

    bf16x8 b0[8], b1[8];
#pragma unroll
    for (int f = 0; f < 8; ++f) b0[f] = *(const bf16x8*)(bbase + f * 512);

    f32x16 accA;
#pragma unroll
    for (int r = 0; r < 16; ++r) accA[r] = 0.f;
    MFMA8(accA, b0);
#pragma unroll
    for (int f = 0; f < 8; ++f) b1[f] = *(const bf16x8*)(bbase + 4096 + f * 512);

#pragma unroll
    for (int t = 1; t < 8; ++t) {
        f32x16 accB;
#pragma unroll
        for (int r = 0; r < 16; ++r) accB[r] = 0.f;
        if (t & 1) { MFMA8(accB, b1); } else { MFMA8(accB, b0); }
        if (t + 1 < 8) {
            const bf16_t* nb = bbase + (size_t)(t + 1) * 4096;
            if (t & 1) {
#pragma unroll
                for (int f = 0; f < 8; ++f) b0[f] = *(const bf16x8*)(nb + f * 512);
            } else {
#pragma unroll
                for (int f = 0; f < 8; ++f) b1[f] = *(const bf16x8*)(nb + f * 512);
            }
        }
        // epilogue for tile t-1 (accA) — uniform flags
        {
            int ct = ci * 8 + (t - 1);
            if (ct >= I) {
                float c0 = 0.f, c1 = 0.f, c2 = 0.f, c3 = 0.f;
#pragma unroll
                for (int r = 0; r < 16; ++r) {
                    float e = __builtin_amdgcn_exp2f(fmaf(accA[r], L2E10, -L2E10));
                    se[r] += e;
                    if ((r & 3) == 0) c0 += e; else if ((r & 3) == 1) c1 += e;
                    else if ((r & 3) == 2) c2 += e; else c3 += e;
                }
                if (ct > I) colacc[t - 1] = (c0 + c1) + (c2 + c3);
            }
        }
        accA = accB;
    }
    {   // epilogue tile 7
        int ct = ci * 8 + 7;
        if (ct >= I) {
            float c0 = 0.f, c1 = 0.f, c2 = 0.f, c3 = 0.f;
#pragma unroll
            for (int r = 0; r < 16; ++r) {
                float e = __builtin_amdgcn_exp2f(fmaf(accA[r], L2E10, -L2E10));
                se[r] += e;
                if ((r & 3) == 0) c0 += e; else if ((r & 3) == 1) c1 += e;
                else if ((r & 3) == 2) c2 += e; else c3 += e;
            }
            if (ct > I) colacc[7] = (c0 + c1) + (c2 + c3);
        }
    }

    // row-side: reduce over 32 columns, atomic into se_acc
#pragma unroll
    for (int r = 0; r < 16; ++r) {
        float vv = se[r];
#pragma unroll
        for (int m = 1; m < 32; m <<= 1) vv += __shfl_xor(vv, m, 64);
        se[r] = vv;
    }
    if (c == 0) {
        int rowbase = I * 32 + 4 * h;
#pragma unroll
        for (int r = 0; r < 16; ++r)
            atomicAdd(&se_acc[rowbase + (r & 3) + 8 * (r >> 2)], se[r]);
    }

    // col-side: combine h halves, LDS-combine the 4 waves (same ci), flush once
#pragma unroll
    for (int t = 0; t < 8; ++t) {
        float v = colacc[t] + __shfl_xor(colacc[t], 32, 64);
        if (h == 0) atomicAdd(&cols[t * 32 + c], v);
    }
    __syncthreads();
    atomicAdd(&se_acc[ci * 256 + threadIdx.x], cols[threadIdx.x]);
}

// --- finalize: per-row loss; wave per 8 rows ---
__global__ __launch_bounds__(256) void finalize_kernel(const bf16_t* __restrict__ xsw,
                                                       const float* __restrict__ se_acc,
                                                       const float* __restrict__ csum,
                                                       const int* __restrict__ hist,
                                                       const int* __restrict__ labels,
                                                       float* __restrict__ out) {
    __shared__ float part[4];
    int wv = threadIdx.x >> 6, lane = threadIdx.x & 63;
    int wid = blockIdx.x * 4 + wv;
    int f = lane >> 3, hh = (lane >> 2) & 1, j = (lane & 3) << 1;
    float lsum = 0.f;
    for (int k = 0; k < 8; ++k) {
        int row = wid * 8 + k;
        int lab = labels[row];
        bf16x2 xv = *(const bf16x2*)(xsw + ((size_t)(row >> 5) * 4096) + f * 512 + hh * 256 + (row & 31) * 8 + j);
        float2 cs = *(const float2*)(csum + (size_t)lab * DIM + 2 * lane);
        float x0 = (float)xv.x, x1 = (float)xv.y;
        float sd = fmaf(x0, x0, x1 * x1);
        float cd = fmaf(x0, cs.x, x1 * cs.y);
#pragma unroll
        for (int m = 1; m < 64; m <<= 1) {
            sd += __shfl_xor(sd, m, 64);
            cd += __shfl_xor(cd, m, 64);
        }
        if (lane == 0) {
            float diag = __builtin_amdgcn_exp2f(fmaf(sd, L2E10, -L2E10));
            float sev  = fmaxf(se_acc[row] - diag, 1e-30f);
            float lse  = fmaf(log2f(sev), LN2, 10.f);
            float cnt  = (float)(hist[lab] - 1);
            float ps   = 10.f * (cd - sd);
            lsum += (cnt * lse - ps) / (cnt + SMALL_VAL);
        }
    }
    if (lane == 0) part[wv] = lsum;
    __syncthreads();
    if (threadIdx.x == 0) atomicAdd(out, part[0] + part[1] + part[2] + part[3]);
}

extern "C" void kernel_launch(void* const* d_in, const int* in_sizes, int n_in,
                              void* d_out, int out_size, void* d_ws, size_t ws_size,
                              hipStream_t stream) {
    const float* emb  = (const float*)d_in[0];
    const int* labels = (const int*)d_in[1];

    char* ws = (char*)d_ws;
    bf16_t* xsw = (bf16_t*)ws;                                    // 2 MB
    float* csum = (float*)(ws + (size_t)NN * DIM * 2);            // 512 KB
    int*   hist = (int*)((char*)csum + (size_t)NCLASS * DIM * 4); // 4 KB
    float* se   = (float*)((char*)hist + NCLASS * 4);             // 32 KB

    normalize_kernel<<<NN / 4, 256, 0, stream>>>(emb, xsw, se, (float*)d_out);
    csum_kernel<<<NCLASS / 4, 256, 0, stream>>>(xsw, labels, csum, hist);
    supcon_main<<<NJOBS / 4, 256, 0, stream>>>(xsw, se);
    finalize_kernel<<<NN / 32, 256, 0, stream>>>(xsw, se, csum, hist, labels, (float*)d_out);
}

// Round 5
// 109.041 us; speedup vs baseline: 1.1974x; 1.1974x over previous
//
#include <hip/hip_runtime.h>
#include <hip/hip_bf16.h>

// SupCon loss, N=8192, D=128, T=0.1.
// R4: (a) csum by block-per-class label scan (1024 blocks, int4 loads, LDS
// combine) instead of 1-wave-per-class ballot-gather (was 45us, occupancy 10%),
// (b) main split into finer upper-triangle jobs (2080 blocks, 8/CU) with lean
// VGPR (launch_bounds(256,4)) — occupancy-based latency hiding, no ping-pong,
// (c) second row-major normalized copy xrow for contiguous gather/finalize.
//
// Math: loss_i = (cnt_i*lse_i - ps_i)/(cnt_i+tiny)
//   lse_i = 10 + ln(sum_{j!=i} e^{s_ij-10})   (constant shift exact; s<=10)
//   ps_i  = 10*(x_i . csum[lab_i] - x_i . x_i)
//   se accumulated INCLUDING diagonal; diag e^{10*selfdot-10} subtracted in
//   finalize. Symmetry: tile (I,ct), ct>I contributes rows AND cols; ct==I rows only.

typedef __bf16 bf16_t;
typedef __bf16 bf16x2 __attribute__((ext_vector_type(2)));
typedef __bf16 bf16x8 __attribute__((ext_vector_type(8)));
typedef float f32x16 __attribute__((ext_vector_type(16)));

#define NN 8192
#define DIM 128
#define NCLASS 1024
#define MAIN_BLOCKS 2080          // sum_{cq=0}^{63} (cq+1)
#define SMALL_VAL 1.17549435e-38f
#define L2E10 14.4269504089f      // 10*log2(e)
#define LN2 0.69314718056f

// Swizzle: X[row][d] at (row>>5)*4096 + (d>>4)*512 + ((d>>3)&1)*256 + (row&31)*8 + (d&7)
// Lane slot: lane l holds dims (2l,2l+1): f=l>>3, hh=(l>>2)&1, j=(l&3)*2.

// --- normalize: swizzled + row-major bf16 stores; zero se_acc and out ---
__global__ __launch_bounds__(256) void normalize_kernel(const float* __restrict__ emb,
                                                        bf16_t* __restrict__ xsw,
                                                        bf16_t* __restrict__ xrow,
                                                        float* __restrict__ se_acc,
                                                        float* __restrict__ out) {
    int row  = blockIdx.x * 4 + (threadIdx.x >> 6);
    int lane = threadIdx.x & 63;
    float2 v = ((const float2*)emb)[row * 64 + lane];
    float ss = v.x * v.x + v.y * v.y;
#pragma unroll
    for (int m = 1; m < 64; m <<= 1) ss += __shfl_xor(ss, m, 64);
    float inv = 1.0f / fmaxf(sqrtf(ss), 1e-12f);
    bf16x2 o; o.x = (bf16_t)(v.x * inv); o.y = (bf16_t)(v.y * inv);
    int f = lane >> 3, hh = (lane >> 2) & 1, j = (lane & 3) << 1;
    *(bf16x2*)(xsw + ((size_t)(row >> 5) * 4096) + f * 512 + hh * 256 + (row & 31) * 8 + j) = o;
    *(bf16x2*)(xrow + (size_t)row * DIM + 2 * lane) = o;
    if (threadIdx.x < 4) se_acc[blockIdx.x * 4 + threadIdx.x] = 0.f;
    if (blockIdx.x == 0 && threadIdx.x == 0) *out = 0.f;
}

// --- class sums: one block per class; 4 waves scan 2048 labels each (int4) ---
__global__ __launch_bounds__(256) void csum_kernel(const bf16_t* __restrict__ xrow,
                                                   const int* __restrict__ labels,
                                                   float* __restrict__ csum,
                                                   int* __restrict__ hist) {
    __shared__ float cs[DIM];
    __shared__ int cw[4];
    int cls = blockIdx.x;
    int wv = threadIdx.x >> 6, lane = threadIdx.x & 63;
    if (threadIdx.x < DIM) cs[threadIdx.x] = 0.f;
    __syncthreads();
    float s0 = 0.f, s1 = 0.f;
    int cnt = 0;
    const int4* lab4 = (const int4*)(labels + wv * 2048);
    for (int it = 0; it < 8; ++it) {
        int4 l = lab4[it * 64 + lane];
        int base = wv * 2048 + it * 256;
#pragma unroll
        for (int cmp = 0; cmp < 4; ++cmp) {
            int li = (cmp == 0) ? l.x : (cmp == 1) ? l.y : (cmp == 2) ? l.z : l.w;
            unsigned long long m = __ballot(li == cls);
            cnt += (int)__popcll(m);
            while (m) {
                int bb = __builtin_ctzll(m);
                m &= m - 1;
                int row = base + 4 * bb + cmp;
                bf16x2 xv = *(const bf16x2*)(xrow + (size_t)row * DIM + 2 * lane);
                s0 += (float)xv.x; s1 += (float)xv.y;
            }
        }
    }
    atomicAdd(&cs[2 * lane], s0);
    atomicAdd(&cs[2 * lane + 1], s1);
    if (lane == 0) cw[wv] = cnt;
    __syncthreads();
    if (threadIdx.x < DIM) csum[(size_t)cls * DIM + threadIdx.x] = cs[threadIdx.x];
    if (threadIdx.x == 0) hist[cls] = cw[0] + cw[1] + cw[2] + cw[3];
}

// --- main: block = (cq, g): col chunk cq (128 cols = 4 tiles), rows 4g..4g+3
// (wave wv -> 32-row band I = 4g+wv, I <= 4cq+3 by construction).
// C layout (m74/m101): col = lane&31, row = (r&3) + 8*(r>>2) + 4*(lane>>5).
__global__ __launch_bounds__(256, 4) void supcon_main(const bf16_t* __restrict__ xsw,
                                                      float* __restrict__ se_acc) {
    __shared__ float cols[128];
    if (threadIdx.x < 128) cols[threadIdx.x] = 0.f;
    __syncthreads();

    int b = blockIdx.x;
    int cq = (int)((sqrtf(8.f * (float)b + 1.f) - 1.f) * 0.5f);
    while ((cq + 1) * (cq + 2) / 2 <= b) ++cq;
    while (cq * (cq + 1) / 2 > b) --cq;
    int g = b - cq * (cq + 1) / 2;

    int wv = threadIdx.x >> 6, lane = threadIdx.x & 63;
    int I = 4 * g + wv;
    int c = lane & 31, h = lane >> 5;
    int laneoff = h * 256 + c * 8;

    const bf16_t* abase = xsw + (size_t)I * 4096 + laneoff;
    bf16x8 a[8];
#pragma unroll
    for (int f = 0; f < 8; ++f) a[f] = *(const bf16x8*)(abase + f * 512);

    const bf16_t* bbase = xsw + (size_t)cq * 4 * 4096 + laneoff;

    float se[16];
#pragma unroll
    for (int r = 0; r < 16; ++r) se[r] = 0.f;
    float colacc[4] = {0.f, 0.f, 0.f, 0.f};

#pragma unroll
    for (int t = 0; t < 4; ++t) {
        const bf16_t* bb = bbase + (size_t)t * 4096;
        bf16x8 bfr[8];
#pragma unroll
        for (int f = 0; f < 8; ++f) bfr[f] = *(const bf16x8*)(bb + f * 512);
        f32x16 acc;
#pragma unroll
        for (int r = 0; r < 16; ++r) acc[r] = 0.f;
#pragma unroll
        for (int f = 0; f < 8; ++f)
            acc = __builtin_amdgcn_mfma_f32_32x32x16_bf16(a[f], bfr[f], acc, 0, 0, 0);
        int ct = cq * 4 + t;
        if (ct >= I) {              // wave-uniform
            float c0 = 0.f, c1 = 0.f, c2 = 0.f, c3 = 0.f;
#pragma unroll
            for (int r = 0; r < 16; ++r) {
                float e = __builtin_amdgcn_exp2f(fmaf(acc[r], L2E10, -L2E10));
                se[r] += e;
                if ((r & 3) == 0) c0 += e; else if ((r & 3) == 1) c1 += e;
                else if ((r & 3) == 2) c2 += e; else c3 += e;
            }
            if (ct > I) colacc[t] = (c0 + c1) + (c2 + c3);
        }
    }

    // row-side: reduce over 32 columns, atomic into se_acc
#pragma unroll
    for (int r = 0; r < 16; ++r) {
        float vv = se[r];
#pragma unroll
        for (int m = 1; m < 32; m <<= 1) vv += __shfl_xor(vv, m, 64);
        se[r] = vv;
    }
    if (c == 0) {
        int rowbase = I * 32 + 4 * h;
#pragma unroll
        for (int r = 0; r < 16; ++r)
            atomicAdd(&se_acc[rowbase + (r & 3) + 8 * (r >> 2)], se[r]);
    }

    // col-side: combine h halves, LDS-combine 4 waves (same cq), flush once
#pragma unroll
    for (int t = 0; t < 4; ++t) {
        float v = colacc[t] + __shfl_xor(colacc[t], 32, 64);
        if (h == 0) atomicAdd(&cols[t * 32 + c], v);
    }
    __syncthreads();
    if (threadIdx.x < 128)
        atomicAdd(&se_acc[cq * 128 + threadIdx.x], cols[threadIdx.x]);
}

// --- finalize: per-row loss; wave per 8 rows; contiguous xrow/csum reads ---
__global__ __launch_bounds__(256) void finalize_kernel(const bf16_t* __restrict__ xrow,
                                                       const float* __restrict__ se_acc,
                                                       const float* __restrict__ csum,
                                                       const int* __restrict__ hist,
                                                       const int* __restrict__ labels,
                                                       float* __restrict__ out) {
    __shared__ float part[4];
    int wv = threadIdx.x >> 6, lane = threadIdx.x & 63;
    int wid = blockIdx.x * 4 + wv;
    float lsum = 0.f;
    for (int k = 0; k < 8; ++k) {
        int row = wid * 8 + k;
        int lab = labels[row];
        bf16x2 xv = *(const bf16x2*)(xrow + (size_t)row * DIM + 2 * lane);
        float2 cs = *(const float2*)(csum + (size_t)lab * DIM + 2 * lane);
        float x0 = (float)xv.x, x1 = (float)xv.y;
        float sd = fmaf(x0, x0, x1 * x1);
        float cd = fmaf(x0, cs.x, x1 * cs.y);
#pragma unroll
        for (int m = 1; m < 64; m <<= 1) {
            sd += __shfl_xor(sd, m, 64);
            cd += __shfl_xor(cd, m, 64);
        }
        if (lane == 0) {
            float diag = __builtin_amdgcn_exp2f(fmaf(sd, L2E10, -L2E10));
            float sev  = fmaxf(se_acc[row] - diag, 1e-30f);
            float lse  = fmaf(log2f(sev), LN2, 10.f);
            float cnt  = (float)(hist[lab] - 1);
            float ps   = 10.f * (cd - sd);
            lsum += (cnt * lse - ps) / (cnt + SMALL_VAL);
        }
    }
    if (lane == 0) part[wv] = lsum;
    __syncthreads();
    if (threadIdx.x == 0) atomicAdd(out, part[0] + part[1] + part[2] + part[3]);
}

extern "C" void kernel_launch(void* const* d_in, const int* in_sizes, int n_in,
                              void* d_out, int out_size, void* d_ws, size_t ws_size,
                              hipStream_t stream) {
    const float* emb  = (const float*)d_in[0];
    const int* labels = (const int*)d_in[1];

    char* ws = (char*)d_ws;
    bf16_t* xsw  = (bf16_t*)ws;                                     // 2 MB swizzled
    bf16_t* xrow = (bf16_t*)(ws + (size_t)NN * DIM * 2);            // 2 MB row-major
    float* csum  = (float*)(ws + 2 * (size_t)NN * DIM * 2);         // 512 KB
    int*   hist  = (int*)((char*)csum + (size_t)NCLASS * DIM * 4);  // 4 KB
    float* se    = (float*)((char*)hist + NCLASS * 4);              // 32 KB

    normalize_kernel<<<NN / 4, 256, 0, stream>>>(emb, xsw, xrow, se, (float*)d_out);
    csum_kernel<<<NCLASS, 256, 0, stream>>>(xrow, labels, csum, hist);
    supcon_main<<<MAIN_BLOCKS, 256, 0, stream>>>(xsw, se);
    finalize_kernel<<<NN / 32, 256, 0, stream>>>(xrow, se, csum, hist, labels, (float*)d_out);
}

// Round 6
// 99.110 us; speedup vs baseline: 1.3174x; 1.1002x over previous
//
#include <hip/hip_runtime.h>
#include <hip/hip_bf16.h>

// SupCon loss, N=8192, D=128, T=0.1.
// R5: 3 nodes. (1) norm_csum: block-per-class; ballot-scan labels, normalize
// member rows from emb (each row done exactly once), LDS class-sum, then
// per-row cd/sd/cnt-1 precompute. (2) main: block stages its shared 32KB
// B-chunk to LDS once (4 waves consume it; was 4x redundant L2 reads),
// triangular 2080-block grid, launch_bounds(256,4) -> 16 waves/CU.
// (3) finalize: pure elementwise loss + reduce.
//
// Math: loss_i = (cm1_i*lse_i - 10*(cd_i - sd_i))/(cm1_i+tiny)
//   lse_i = 10 + ln(sum_{j!=i} e^{s_ij-10})  (constant shift exact; s<=10)
//   cd_i = x_i . classsum[lab_i], sd_i = x_i . x_i (bf16-rounded inputs,
//   consistent with the MFMA path). se accumulated INCLUDING diagonal;
//   diag e^{10*sd-10} subtracted in finalize.
//   Symmetry: tile (I,ct), ct>I feeds rows AND cols; ct==I rows only.

typedef __bf16 bf16_t;
typedef __bf16 bf16x2 __attribute__((ext_vector_type(2)));
typedef __bf16 bf16x8 __attribute__((ext_vector_type(8)));
typedef float f32x16 __attribute__((ext_vector_type(16)));

#define NN 8192
#define DIM 128
#define MAIN_BLOCKS 2080          // sum_{cq=0}^{63} (cq+1)
#define SMALL_VAL 1.17549435e-38f
#define L2E10 14.4269504089f      // 10*log2(e)
#define LN2 0.69314718056f

// Swizzle: X[row][d] at (row>>5)*4096 + (d>>4)*512 + ((d>>3)&1)*256 + (row&31)*8 + (d&7)
// Lane l holds dims (2l, 2l+1): f=l>>3, hh=(l>>2)&1, j=(l&3)*2 (pair contiguous).
__device__ inline size_t swz(int row, int lane) {
    int f = lane >> 3, hh = (lane >> 2) & 1, j = (lane & 3) << 1;
    return ((size_t)(row >> 5) * 4096) + f * 512 + hh * 256 + (row & 31) * 8 + j;
}

// --- fused normalize + class-sum + per-row finalize scalars ---
__global__ __launch_bounds__(256) void norm_csum(const float* __restrict__ emb,
                                                 const int* __restrict__ labels,
                                                 bf16_t* __restrict__ xsw,
                                                 float* __restrict__ cd_arr,
                                                 float* __restrict__ sd_arr,
                                                 float* __restrict__ cm1_arr,
                                                 float* __restrict__ se_acc,
                                                 float* __restrict__ out) {
    __shared__ float cs[DIM];
    __shared__ int rowlist[96];
    __shared__ int nrows;
    int cls = blockIdx.x;                      // 1024 blocks; labels < 1000
    int wv = threadIdx.x >> 6, lane = threadIdx.x & 63;
    if (threadIdx.x < DIM) cs[threadIdx.x] = 0.f;
    if (threadIdx.x == 0) nrows = 0;
    if (threadIdx.x < 8) se_acc[cls * 8 + threadIdx.x] = 0.f;   // zero all 8192
    if (cls == 0 && threadIdx.x == 0) *out = 0.f;
    __syncthreads();

    float s0 = 0.f, s1 = 0.f;
    const int4* lab4 = (const int4*)(labels + wv * 2048);       // wave's quarter
#pragma unroll
    for (int it = 0; it < 8; ++it) {
        int4 l = lab4[it * 64 + lane];
        int base = wv * 2048 + it * 256;
#pragma unroll
        for (int cmp = 0; cmp < 4; ++cmp) {
            int li = (cmp == 0) ? l.x : (cmp == 1) ? l.y : (cmp == 2) ? l.z : l.w;
            unsigned long long m = __ballot(li == cls);
            while (m) {                         // wave-uniform loop, ~2 rows/wave avg
                int bb = __builtin_ctzll(m);
                m &= m - 1;
                int row = base + 4 * bb + cmp;
                float2 v = ((const float2*)emb)[row * 64 + lane];
                float ss = fmaf(v.x, v.x, v.y * v.y);
#pragma unroll
                for (int mm = 1; mm < 64; mm <<= 1) ss += __shfl_xor(ss, mm, 64);
                float inv = 1.0f / fmaxf(sqrtf(ss), 1e-12f);
                bf16x2 o; o.x = (bf16_t)(v.x * inv); o.y = (bf16_t)(v.y * inv);
                *(bf16x2*)(xsw + swz(row, lane)) = o;
                s0 += (float)o.x; s1 += (float)o.y;     // bf16-rounded, matches MFMA
                if (lane == 0) {
                    int idx = atomicAdd(&nrows, 1);
                    if (idx < 96) rowlist[idx] = row;
                }
            }
        }
    }
    atomicAdd(&cs[2 * lane], s0);
    atomicAdd(&cs[2 * lane + 1], s1);
    __syncthreads();
    int n = nrows;
    for (int k = wv; k < n; k += 4) {          // per-row cd/sd (rows split over waves)
        int row = rowlist[k];
        bf16x2 xv = *(const bf16x2*)(xsw + swz(row, lane));
        float x0 = (float)xv.x, x1 = (float)xv.y;
        float cdp = fmaf(x0, cs[2 * lane], x1 * cs[2 * lane + 1]);
        float sdp = fmaf(x0, x0, x1 * x1);
#pragma unroll
        for (int mm = 1; mm < 64; mm <<= 1) {
            cdp += __shfl_xor(cdp, mm, 64);
            sdp += __shfl_xor(sdp, mm, 64);
        }
        if (lane == 0) {
            cd_arr[row] = cdp; sd_arr[row] = sdp; cm1_arr[row] = (float)(n - 1);
        }
    }
}

// --- main: block = (cq, g): 128-col chunk staged to LDS once; wave wv -> row
// band I = 4g+wv (I <= 4cq+3). C layout (m74/m101): col = lane&31,
// row = (r&3) + 8*(r>>2) + 4*(lane>>5).
__global__ __launch_bounds__(256, 4) void supcon_main(const bf16_t* __restrict__ xsw,
                                                      float* __restrict__ se_acc) {
    __shared__ bf16_t bst[4 * 4096];           // 32 KB: the 4 shared B tiles
    __shared__ float cols[128];
    if (threadIdx.x < 128) cols[threadIdx.x] = 0.f;

    int b = blockIdx.x;                        // triangular decode
    int cq = (int)((sqrtf(8.f * (float)b + 1.f) - 1.f) * 0.5f);
    while ((cq + 1) * (cq + 2) / 2 <= b) ++cq;
    while (cq * (cq + 1) / 2 > b) --cq;
    int g = b - cq * (cq + 1) / 2;

    int wv = threadIdx.x >> 6, lane = threadIdx.x & 63;
    int I = 4 * g + wv;
    int c = lane & 31, h = lane >> 5;
    int laneoff = h * 256 + c * 8;

    // A frags (global, per wave) — issued before staging so latencies overlap
    const bf16_t* abase = xsw + (size_t)I * 4096 + laneoff;
    bf16x8 a[8];
#pragma unroll
    for (int f = 0; f < 8; ++f) a[f] = *(const bf16x8*)(abase + f * 512);

    // stage B chunk (32 KB) once for all 4 waves
    {
        const uint4* gsrc = (const uint4*)(xsw + (size_t)cq * 4 * 4096);
        uint4* ldst = (uint4*)bst;
#pragma unroll
        for (int i = 0; i < 8; ++i)
            ldst[i * 256 + threadIdx.x] = gsrc[i * 256 + threadIdx.x];
    }
    __syncthreads();

    float se[16];
#pragma unroll
    for (int r = 0; r < 16; ++r) se[r] = 0.f;
    float colacc[4] = {0.f, 0.f, 0.f, 0.f};

#pragma unroll
    for (int t = 0; t < 4; ++t) {
        const bf16_t* bt = bst + t * 4096 + laneoff;
        bf16x8 bfr[8];
#pragma unroll
        for (int f = 0; f < 8; ++f) bfr[f] = *(const bf16x8*)(bt + f * 512);
        f32x16 acc;
#pragma unroll
        for (int r = 0; r < 16; ++r) acc[r] = 0.f;
#pragma unroll
        for (int f = 0; f < 8; ++f)
            acc = __builtin_amdgcn_mfma_f32_32x32x16_bf16(a[f], bfr[f], acc, 0, 0, 0);
        int ct = cq * 4 + t;
        if (ct >= I) {                          // wave-uniform mask
            float c0 = 0.f, c1 = 0.f, c2 = 0.f, c3 = 0.f;
#pragma unroll
            for (int r = 0; r < 16; ++r) {
                float e = __builtin_amdgcn_exp2f(fmaf(acc[r], L2E10, -L2E10));
                se[r] += e;
                if ((r & 3) == 0) c0 += e; else if ((r & 3) == 1) c1 += e;
                else if ((r & 3) == 2) c2 += e; else c3 += e;
            }
            if (ct > I) colacc[t] = (c0 + c1) + (c2 + c3);
        }
    }

    // row-side: reduce over 32 columns, atomic into se_acc
#pragma unroll
    for (int r = 0; r < 16; ++r) {
        float vv = se[r];
#pragma unroll
        for (int m = 1; m < 32; m <<= 1) vv += __shfl_xor(vv, m, 64);
        se[r] = vv;
    }
    if (c == 0) {
        int rowbase = I * 32 + 4 * h;
#pragma unroll
        for (int r = 0; r < 16; ++r)
            atomicAdd(&se_acc[rowbase + (r & 3) + 8 * (r >> 2)], se[r]);
    }

    // col-side: combine halves, LDS-combine 4 waves (same cq), flush once
#pragma unroll
    for (int t = 0; t < 4; ++t) {
        float v = colacc[t] + __shfl_xor(colacc[t], 32, 64);
        if (h == 0) atomicAdd(&cols[t * 32 + c], v);
    }
    __syncthreads();
    if (threadIdx.x < 128)
        atomicAdd(&se_acc[cq * 128 + threadIdx.x], cols[threadIdx.x]);
}

// --- finalize: elementwise loss from precomputed scalars, block reduce ---
__global__ __launch_bounds__(256) void finalize_kernel(const float* __restrict__ se_acc,
                                                       const float* __restrict__ cd_arr,
                                                       const float* __restrict__ sd_arr,
                                                       const float* __restrict__ cm1_arr,
                                                       float* __restrict__ out) {
    __shared__ float part[4];
    int i = blockIdx.x * 256 + threadIdx.x;
    float sd = sd_arr[i], cd = cd_arr[i], cm1 = cm1_arr[i];
    float diag = __builtin_amdgcn_exp2f(fmaf(sd, L2E10, -L2E10));
    float sev  = fmaxf(se_acc[i] - diag, 1e-30f);
    float lse  = fmaf(__builtin_amdgcn_logf(sev), LN2, 10.f);   // v_log = log2
    float loss = (cm1 * lse - 10.f * (cd - sd)) / (cm1 + SMALL_VAL);
#pragma unroll
    for (int m = 1; m < 64; m <<= 1) loss += __shfl_xor(loss, m, 64);
    int wv = threadIdx.x >> 6;
    if ((threadIdx.x & 63) == 0) part[wv] = loss;
    __syncthreads();
    if (threadIdx.x == 0) atomicAdd(out, part[0] + part[1] + part[2] + part[3]);
}

extern "C" void kernel_launch(void* const* d_in, const int* in_sizes, int n_in,
                              void* d_out, int out_size, void* d_ws, size_t ws_size,
                              hipStream_t stream) {
    const float* emb  = (const float*)d_in[0];
    const int* labels = (const int*)d_in[1];

    char* ws = (char*)d_ws;
    bf16_t* xsw = (bf16_t*)ws;                          // 2 MB swizzled normalized X
    float* se   = (float*)(ws + (size_t)NN * DIM * 2);  // 32 KB
    float* cd   = se + NN;                              // 32 KB
    float* sd   = cd + NN;                              // 32 KB
    float* cm1  = sd + NN;                              // 32 KB

    norm_csum<<<1024, 256, 0, stream>>>(emb, labels, xsw, cd, sd, cm1, se, (float*)d_out);
    supcon_main<<<MAIN_BLOCKS, 256, 0, stream>>>(xsw, se);
    finalize_kernel<<<NN / 256, 256, 0, stream>>>(se, cd, sd, cm1, (float*)d_out);
}